// Round 1
// 1073.320 us; speedup vs baseline: 1.2740x; 1.2740x over previous
//
#include <hip/hip_runtime.h>

#define S_LEN 2048
#define NB 2
#define NH 32
#define NKV 8
#define HD 128
#define HID 4096
#define NQKV 6144

using bf16x8 = __attribute__((ext_vector_type(8))) __bf16;
using f32x4  = __attribute__((ext_vector_type(4))) float;

__device__ __forceinline__ ushort f2b(float f) {
  uint u = __builtin_bit_cast(uint, f);
  u += 0x7fffu + ((u >> 16) & 1u);
  return (ushort)(u >> 16);
}
__device__ __forceinline__ float b2f(ushort h) {
  uint u = ((uint)h) << 16;
  return __builtin_bit_cast(float, u);
}

__device__ __forceinline__ uint cvt_pk_bf16(float lo, float hi) {
  uint r;
  asm("v_cvt_pk_bf16_f32 %0, %1, %2" : "=v"(r) : "v"(lo), "v"(hi));
  return r;
}

__device__ __forceinline__ void gld16(const void* g, void* l) {
  __builtin_amdgcn_global_load_lds((const __attribute__((address_space(1))) void*)g,
                                   (__attribute__((address_space(3))) void*)l, 16, 0, 0);
}

__device__ __forceinline__ void stc(float* C, size_t i, float v)  { C[i] = v; }
__device__ __forceinline__ void stc(ushort* C, size_t i, float v) { C[i] = f2b(v); }

// ---------------- f32 -> bf16 elementwise ----------------
__global__ void cvt_bf16(const float* __restrict__ src, ushort* __restrict__ dst, int n) {
  int i = (blockIdx.x * 256 + threadIdx.x) * 4;
  if (i < n) {
    float4 v = *(const float4*)(src + i);
    *(ushort4*)(dst + i) = make_ushort4(f2b(v.x), f2b(v.y), f2b(v.z), f2b(v.w));
  }
}

// ---------------- f32 [R][C] -> bf16 [C][R] transpose (padded tile, conflict-free) ----
__global__ void trans_f32_bf16(const float* __restrict__ src, ushort* __restrict__ dst,
                               int R, int C) {
  __shared__ float tile[32][33];
  const int c0 = blockIdx.x * 32, r0 = blockIdx.y * 32;
  const int x = threadIdx.x, y = threadIdx.y;  // block (32,8)
#pragma unroll
  for (int i = 0; i < 32; i += 8)
    tile[y + i][x] = src[(size_t)(r0 + y + i) * C + (c0 + x)];
  __syncthreads();
#pragma unroll
  for (int i = 0; i < 32; i += 8)
    dst[(size_t)(c0 + y + i) * R + (r0 + x)] = f2b(tile[x][y + i]);
}

// ---------------- bf16 NT GEMM (m97 structure): C[M][N] = A[M][K] * Bt[N][K]^T ------
template <typename OutT>
__global__ __launch_bounds__(256) void gemm_nt(const ushort* __restrict__ A,
                                               const ushort* __restrict__ Bt,
                                               OutT* __restrict__ C,
                                               int M, int N, int K, int lda, int ldb) {
  __shared__ ushort As[128 * 32];
  __shared__ ushort Bs[128 * 32];
  const int tid  = threadIdx.x;
  const int wave = tid >> 6;
  const int lane = tid & 63;
  const int lr = lane & 15, lg = lane >> 4;
  const int m0 = blockIdx.y * 128, n0 = blockIdx.x * 128;
  const int wm = (wave >> 1) * 64, wn = (wave & 1) * 64;

  f32x4 acc[4][4];
#pragma unroll
  for (int i = 0; i < 4; ++i)
#pragma unroll
    for (int j = 0; j < 4; ++j) acc[i][j] = (f32x4){0.f, 0.f, 0.f, 0.f};

  for (int kt = 0; kt < K; kt += 32) {
    __syncthreads();
#pragma unroll
    for (int it = 0; it < 2; ++it) {
      const int cbase = it * 256 + wave * 64;  // wave-uniform LDS base
      const int c = cbase + lane;
      const int row = c >> 2, kc = c & 3;
      gld16(A  + (size_t)(m0 + row) * lda + kt + kc * 8, As + cbase * 8);
      gld16(Bt + (size_t)(n0 + row) * ldb + kt + kc * 8, Bs + cbase * 8);
    }
    __syncthreads();
    bf16x8 af[4], bfg[4];
#pragma unroll
    for (int i = 0; i < 4; ++i) {
      af[i]  = *(const bf16x8*)(As + (wm + i * 16 + lr) * 32 + lg * 8);
      bfg[i] = *(const bf16x8*)(Bs + (wn + i * 16 + lr) * 32 + lg * 8);
    }
#pragma unroll
    for (int i = 0; i < 4; ++i)
#pragma unroll
      for (int j = 0; j < 4; ++j)
        acc[i][j] = __builtin_amdgcn_mfma_f32_16x16x32_bf16(af[i], bfg[j], acc[i][j], 0, 0, 0);
  }

#pragma unroll
  for (int i = 0; i < 4; ++i)
#pragma unroll
    for (int j = 0; j < 4; ++j)
#pragma unroll
      for (int r = 0; r < 4; ++r) {
        const int row = m0 + wm + i * 16 + lg * 4 + r;
        const int col = n0 + wn + j * 16 + lr;
        stc(C, (size_t)row * N + col, acc[i][j][r]);
      }
}

// ---------------- RoPE in-place on q/k heads of qkv (bf16) ----------------
__global__ __launch_bounds__(256) void rope_qk(ushort* __restrict__ qkv) {
  int t = blockIdx.x * 256 + threadIdx.x;
  const int i = t & 63;
  t >>= 6;
  const int head  = t % (NH + NKV);
  const int token = t / (NH + NKV);
  const int s = token & (S_LEN - 1);
  const size_t base = (size_t)token * NQKV + (head < NH ? head * HD : HID + (head - NH) * HD);
  const float x1 = b2f(qkv[base + i]);
  const float x2 = b2f(qkv[base + 64 + i]);
  const float invf = exp2f(-(float)i * 0.2076205059304602f);  // 10000^(-i/64)
  const float fr = (float)s * invf;
  float cs, sn;
  sincosf(fr, &sn, &cs);  // sincosf writes SIN first, COS second
  float o1 = x1 * cs - x2 * sn;
  float o2 = x2 * cs + x1 * sn;
  if (head < NH) {
    o1 *= 0.08838834764831845f;  // 1/sqrt(128) pre-applied to Q
    o2 *= 0.08838834764831845f;
  }
  qkv[base + i]      = f2b(o1);
  qkv[base + 64 + i] = f2b(o2);
}

// ---------------- V: qkv[token][5120+kv*128+d] -> Vt[b*8+kv][d][s] ----------------
__global__ void vtrans(const ushort* __restrict__ qkv, ushort* __restrict__ Vt) {
  __shared__ ushort tile[32][33];
  const int dt = blockIdx.x * 32, st = blockIdx.y * 32, bk = blockIdx.z;
  const int b = bk >> 3, kv = bk & 7;
  const int x = threadIdx.x, y = threadIdx.y;  // (32,8)
#pragma unroll
  for (int i = 0; i < 32; i += 8)
    tile[y + i][x] =
        qkv[(size_t)(b * S_LEN + st + y + i) * NQKV + 5120 + kv * HD + dt + x];
  __syncthreads();
#pragma unroll
  for (int i = 0; i < 32; i += 8)
    Vt[((size_t)bk * HD + dt + y + i) * S_LEN + st + x] = tile[x][y + i];
}

// ---------------- flash attention v2 ----------------
// Block = 256 threads = 4 waves = the 4 q-heads of one kv-head; each wave owns 32
// q rows (two 16-row MFMA tiles). Swapped QK^T (mfma(K,Q) -> S^T) makes the
// softmax row-reduction lane-local: per lane q = lane&15, k spread over regs +
// lg groups => 7 in-lane max/sum ops + 2 shfl_xor. No __syncthreads anywhere
// (per-wave private P tile in LDS, padded to 40-ushort rows => <=2-way banks).
// Defer-max (THR=8) skips the O-rescale on most tiles.
__global__ __launch_bounds__(256) void attn_fa(ushort* __restrict__ qkv,
                                               const ushort* __restrict__ Vt) {
  // XCD-contiguous swizzle: 1024 blocks, 128 consecutive per XCD => each XCD's
  // L2 touches only ~2 (b,kvh) K/V working sets (~2 MB) instead of all 16.
  const int lin = blockIdx.x + 64 * blockIdx.y + 512 * blockIdx.z;
  const int swz = (lin & 7) * 128 + (lin >> 3);
  const int qt = swz & 63;
  const int g  = swz >> 6;
  const int kvh = g & 7;
  const int b   = g >> 3;

  const int wid  = threadIdx.x >> 6;
  const int lane = threadIdx.x & 63;
  const int lr = lane & 15, lg = lane >> 4;
  const int q0 = qt * 32;
  const int h  = kvh * 4 + wid;

  const ushort* Q = qkv + (size_t)(b * S_LEN + q0) * NQKV + h * HD;
  const ushort* K = qkv + (size_t)(b * S_LEN) * NQKV + HID + kvh * HD;
  const ushort* V = Vt + (size_t)(b * NKV + kvh) * (HD * S_LEN);

  __shared__ ushort P[4][2][16 * 40];  // [wave][qtile][row][k padded 32->40]

  // Q fragments: qf[t][kb] = Q[t*16+lr][kb*32 + lg*8 .. +7]
  bf16x8 qf[2][4];
#pragma unroll
  for (int t = 0; t < 2; ++t)
#pragma unroll
    for (int kb = 0; kb < 4; ++kb)
      qf[t][kb] = *(const bf16x8*)(Q + (size_t)(t * 16 + lr) * NQKV + kb * 32 + lg * 8);

  f32x4 o[2][8];
#pragma unroll
  for (int t = 0; t < 2; ++t)
#pragma unroll
    for (int c = 0; c < 8; ++c) o[t][c] = (f32x4){0.f, 0.f, 0.f, 0.f};
  float mi[2] = {-1e30f, -1e30f};
  float li[2] = {0.f, 0.f};

  for (int k0 = 0; k0 <= q0; k0 += 32) {
    const bool diag = (k0 == q0);

    // S^T[k][q] = mfma(K,Q): col(lr)=q within tile t, row(lg*4+r)=k within u.
    f32x4 s[2][2];
#pragma unroll
    for (int t = 0; t < 2; ++t)
#pragma unroll
      for (int u = 0; u < 2; ++u) s[t][u] = (f32x4){0.f, 0.f, 0.f, 0.f};

    __builtin_amdgcn_s_setprio(1);
#pragma unroll
    for (int kb = 0; kb < 4; ++kb) {
      bf16x8 kf0 = *(const bf16x8*)(K + (size_t)(k0 + lr) * NQKV + kb * 32 + lg * 8);
      bf16x8 kf1 = *(const bf16x8*)(K + (size_t)(k0 + 16 + lr) * NQKV + kb * 32 + lg * 8);
      s[0][0] = __builtin_amdgcn_mfma_f32_16x16x32_bf16(kf0, qf[0][kb], s[0][0], 0, 0, 0);
      s[1][0] = __builtin_amdgcn_mfma_f32_16x16x32_bf16(kf0, qf[1][kb], s[1][0], 0, 0, 0);
      s[0][1] = __builtin_amdgcn_mfma_f32_16x16x32_bf16(kf1, qf[0][kb], s[0][1], 0, 0, 0);
      s[1][1] = __builtin_amdgcn_mfma_f32_16x16x32_bf16(kf1, qf[1][kb], s[1][1], 0, 0, 0);
    }
    __builtin_amdgcn_s_setprio(0);

    if (diag) {  // causal mask, only the diagonal tile needs it (k0 == q0)
#pragma unroll
      for (int t = 0; t < 2; ++t)
#pragma unroll
        for (int u = 0; u < 2; ++u)
#pragma unroll
          for (int r = 0; r < 4; ++r)
            if (u * 16 + lg * 4 + r > t * 16 + lr) s[t][u][r] = -1e30f;
    }

    // per-q-row (lane-local) tile max, then combine the 4 lg groups
    float mx[2];
#pragma unroll
    for (int t = 0; t < 2; ++t) {
      float a = fmaxf(fmaxf(s[t][0][0], s[t][0][1]), fmaxf(s[t][0][2], s[t][0][3]));
      float c = fmaxf(fmaxf(s[t][1][0], s[t][1][1]), fmaxf(s[t][1][2], s[t][1][3]));
      float m = fmaxf(a, c);
      m = fmaxf(m, __shfl_xor(m, 16));
      m = fmaxf(m, __shfl_xor(m, 32));
      mx[t] = m;
    }

    // defer-max: only rescale O/li when the max grew by more than THR=8
    if (__any((mx[0] > mi[0] + 8.f) || (mx[1] > mi[1] + 8.f))) {
#pragma unroll
      for (int t = 0; t < 2; ++t) {
        const float mn = fmaxf(mi[t], mx[t]);
        const float al = __expf(mi[t] - mn);
        mi[t] = mn;
        li[t] *= al;
#pragma unroll
        for (int r = 0; r < 4; ++r) {
          const float ar = __shfl(al, lg * 4 + r);  // al is f(lr); o rows are q=lg*4+r
#pragma unroll
          for (int c = 0; c < 8; ++c) o[t][c][r] *= ar;
        }
      }
    }

#pragma unroll
    for (int t = 0; t < 2; ++t) {
      float p[2][4];
#pragma unroll
      for (int u = 0; u < 2; ++u)
#pragma unroll
        for (int r = 0; r < 4; ++r) p[u][r] = __expf(s[t][u][r] - mi[t]);
      float rs = ((p[0][0] + p[0][1]) + (p[0][2] + p[0][3])) +
                 ((p[1][0] + p[1][1]) + (p[1][2] + p[1][3]));
      rs += __shfl_xor(rs, 16);
      rs += __shfl_xor(rs, 32);
      li[t] += rs;
      ushort* Pw = &P[wid][t][0];
#pragma unroll
      for (int u = 0; u < 2; ++u) {
        const uint w0 = cvt_pk_bf16(p[u][0], p[u][1]);
        const uint w1 = cvt_pk_bf16(p[u][2], p[u][3]);
        *(uint2*)(Pw + lr * 40 + u * 16 + lg * 4) = make_uint2(w0, w1);
      }
    }
    // A-fragment of P: row=lr, k=lg*8..+7 (in-wave LDS transpose, no barrier)
    const bf16x8 pa0 = *(const bf16x8*)(&P[wid][0][0] + lr * 40 + lg * 8);
    const bf16x8 pa1 = *(const bf16x8*)(&P[wid][1][0] + lr * 40 + lg * 8);

    __builtin_amdgcn_s_setprio(1);
#pragma unroll
    for (int c = 0; c < 8; ++c) {
      bf16x8 vf = *(const bf16x8*)(V + (size_t)(c * 16 + lr) * S_LEN + k0 + lg * 8);
      o[0][c] = __builtin_amdgcn_mfma_f32_16x16x32_bf16(pa0, vf, o[0][c], 0, 0, 0);
      o[1][c] = __builtin_amdgcn_mfma_f32_16x16x32_bf16(pa1, vf, o[1][c], 0, 0, 0);
    }
    __builtin_amdgcn_s_setprio(0);
  }

#pragma unroll
  for (int t = 0; t < 2; ++t) {
    const float inv = 1.f / li[t];  // per lane: q = lr
#pragma unroll
    for (int r = 0; r < 4; ++r) {
      const float ir = __shfl(inv, lg * 4 + r);
      const size_t row = (size_t)(b * S_LEN + q0 + t * 16 + lg * 4 + r) * NQKV + h * HD;
#pragma unroll
      for (int c = 0; c < 8; ++c) qkv[row + c * 16 + lr] = f2b(o[t][c][r] * ir);
    }
  }
}

extern "C" void kernel_launch(void* const* d_in, const int* in_sizes, int n_in,
                              void* d_out, int out_size, void* d_ws, size_t ws_size,
                              hipStream_t stream) {
  const float* hidden = (const float*)d_in[1];
  const float* w_qkv  = (const float*)d_in[2];
  const float* w_o    = (const float*)d_in[3];
  float* out = (float*)d_out;
  char* ws = (char*)d_ws;

  // workspace layout (128 MiB):
  // R0 [0, 48 MiB)   : wqkvT bf16 [6144][4096]; after gemm1: Vt bf16 [16][128][2048]
  // R1 [48, 80 MiB)  : hb bf16 [4096][4096];    after gemm1: woT bf16 [4096][4096]
  // R2 [80, 128 MiB) : qkv bf16 [4096][6144]; rope in-place; attn into q slots
  ushort* wqkvT = (ushort*)(ws);
  ushort* Vt    = (ushort*)(ws);
  ushort* hb    = (ushort*)(ws + (48u << 20));
  ushort* woT   = (ushort*)(ws + (48u << 20));
  ushort* qkvb  = (ushort*)(ws + (80u << 20));

  // 1) weight + activation prep
  trans_f32_bf16<<<dim3(192, 128), dim3(32, 8), 0, stream>>>(w_qkv, wqkvT, HID, NQKV);
  cvt_bf16<<<16384, 256, 0, stream>>>(hidden, hb, NB * S_LEN * HID);
  // 2) qkv = hb @ wqkvT^T
  gemm_nt<ushort><<<dim3(48, 32), 256, 0, stream>>>(
      hb, wqkvT, qkvb, NB * S_LEN, NQKV, HID, HID, HID);
  // 3) RoPE in-place (q pre-scaled by 1/sqrt(D))
  rope_qk<<<40960, 256, 0, stream>>>(qkvb);
  // 4) V -> Vt[d][s]  (into dead wqkvT region)
  vtrans<<<dim3(4, 64, 16), dim3(32, 8), 0, stream>>>(qkvb, Vt);
  // 5) w_o -> woT (into dead hb region)
  trans_f32_bf16<<<dim3(128, 128), dim3(32, 8), 0, stream>>>(w_o, woT, HID, HID);
  // 6) flash attention v2: block = 4 q-heads of one kv-head, 32 q rows/wave
  attn_fa<<<dim3(64, 8, 2), 256, 0, stream>>>(qkvb, Vt);
  // 7) out = attn @ woT^T
  gemm_nt<float><<<dim3(32, 32), 256, 0, stream>>>(
      qkvb, woT, out, NB * S_LEN, HID, HID, NQKV, HID);
}

// Round 2
// 953.346 us; speedup vs baseline: 1.4343x; 1.1258x over previous
//
#include <hip/hip_runtime.h>

#define S_LEN 2048
#define NB 2
#define NH 32
#define NKV 8
#define HD 128
#define HID 4096
#define NQKV 6144

using bf16x8 = __attribute__((ext_vector_type(8))) __bf16;
using f32x4  = __attribute__((ext_vector_type(4))) float;

__device__ __forceinline__ ushort f2b(float f) {
  uint u = __builtin_bit_cast(uint, f);
  u += 0x7fffu + ((u >> 16) & 1u);
  return (ushort)(u >> 16);
}
__device__ __forceinline__ float b2f(ushort h) {
  uint u = ((uint)h) << 16;
  return __builtin_bit_cast(float, u);
}

__device__ __forceinline__ uint cvt_pk_bf16(float lo, float hi) {
  uint r;
  asm("v_cvt_pk_bf16_f32 %0, %1, %2" : "=v"(r) : "v"(lo), "v"(hi));
  return r;
}

__device__ __forceinline__ void gld16(const void* g, void* l) {
  __builtin_amdgcn_global_load_lds((const __attribute__((address_space(1))) void*)g,
                                   (__attribute__((address_space(3))) void*)l, 16, 0, 0);
}

__device__ __forceinline__ void stc(float* C, size_t i, float v)  { C[i] = v; }
__device__ __forceinline__ void stc(ushort* C, size_t i, float v) { C[i] = f2b(v); }

// ---------------- f32 -> bf16 elementwise ----------------
__global__ void cvt_bf16(const float* __restrict__ src, ushort* __restrict__ dst, int n) {
  int i = (blockIdx.x * 256 + threadIdx.x) * 4;
  if (i < n) {
    float4 v = *(const float4*)(src + i);
    *(ushort4*)(dst + i) = make_ushort4(f2b(v.x), f2b(v.y), f2b(v.z), f2b(v.w));
  }
}

// ---------------- f32 [R][C] -> bf16 [C][R] transpose (padded tile, conflict-free) ----
__global__ void trans_f32_bf16(const float* __restrict__ src, ushort* __restrict__ dst,
                               int R, int C) {
  __shared__ float tile[32][33];
  const int c0 = blockIdx.x * 32, r0 = blockIdx.y * 32;
  const int x = threadIdx.x, y = threadIdx.y;  // block (32,8)
#pragma unroll
  for (int i = 0; i < 32; i += 8)
    tile[y + i][x] = src[(size_t)(r0 + y + i) * C + (c0 + x)];
  __syncthreads();
#pragma unroll
  for (int i = 0; i < 32; i += 8)
    dst[(size_t)(c0 + y + i) * R + (r0 + x)] = f2b(tile[x][y + i]);
}

// ---------------- bf16 NT GEMM (m97 structure): C[M][N] = A[M][K] * Bt[N][K]^T ------
template <typename OutT>
__global__ __launch_bounds__(256) void gemm_nt(const ushort* __restrict__ A,
                                               const ushort* __restrict__ Bt,
                                               OutT* __restrict__ C,
                                               int M, int N, int K, int lda, int ldb) {
  __shared__ ushort As[128 * 32];
  __shared__ ushort Bs[128 * 32];
  const int tid  = threadIdx.x;
  const int wave = tid >> 6;
  const int lane = tid & 63;
  const int lr = lane & 15, lg = lane >> 4;
  const int m0 = blockIdx.y * 128, n0 = blockIdx.x * 128;
  const int wm = (wave >> 1) * 64, wn = (wave & 1) * 64;

  f32x4 acc[4][4];
#pragma unroll
  for (int i = 0; i < 4; ++i)
#pragma unroll
    for (int j = 0; j < 4; ++j) acc[i][j] = (f32x4){0.f, 0.f, 0.f, 0.f};

  for (int kt = 0; kt < K; kt += 32) {
    __syncthreads();
#pragma unroll
    for (int it = 0; it < 2; ++it) {
      const int cbase = it * 256 + wave * 64;  // wave-uniform LDS base
      const int c = cbase + lane;
      const int row = c >> 2, kc = c & 3;
      gld16(A  + (size_t)(m0 + row) * lda + kt + kc * 8, As + cbase * 8);
      gld16(Bt + (size_t)(n0 + row) * ldb + kt + kc * 8, Bs + cbase * 8);
    }
    __syncthreads();
    bf16x8 af[4], bfg[4];
#pragma unroll
    for (int i = 0; i < 4; ++i) {
      af[i]  = *(const bf16x8*)(As + (wm + i * 16 + lr) * 32 + lg * 8);
      bfg[i] = *(const bf16x8*)(Bs + (wn + i * 16 + lr) * 32 + lg * 8);
    }
#pragma unroll
    for (int i = 0; i < 4; ++i)
#pragma unroll
      for (int j = 0; j < 4; ++j)
        acc[i][j] = __builtin_amdgcn_mfma_f32_16x16x32_bf16(af[i], bfg[j], acc[i][j], 0, 0, 0);
  }

#pragma unroll
  for (int i = 0; i < 4; ++i)
#pragma unroll
    for (int j = 0; j < 4; ++j)
#pragma unroll
      for (int r = 0; r < 4; ++r) {
        const int row = m0 + wm + i * 16 + lg * 4 + r;
        const int col = n0 + wn + j * 16 + lr;
        stc(C, (size_t)row * N + col, acc[i][j][r]);
      }
}

// ---------------- RoPE in-place on q/k heads of qkv (bf16) ----------------
__global__ __launch_bounds__(256) void rope_qk(ushort* __restrict__ qkv) {
  int t = blockIdx.x * 256 + threadIdx.x;
  const int i = t & 63;
  t >>= 6;
  const int head  = t % (NH + NKV);
  const int token = t / (NH + NKV);
  const int s = token & (S_LEN - 1);
  const size_t base = (size_t)token * NQKV + (head < NH ? head * HD : HID + (head - NH) * HD);
  const float x1 = b2f(qkv[base + i]);
  const float x2 = b2f(qkv[base + 64 + i]);
  const float invf = exp2f(-(float)i * 0.2076205059304602f);  // 10000^(-i/64)
  const float fr = (float)s * invf;
  float cs, sn;
  sincosf(fr, &sn, &cs);  // sincosf writes SIN first, COS second
  float o1 = x1 * cs - x2 * sn;
  float o2 = x2 * cs + x1 * sn;
  if (head < NH) {
    o1 *= 0.08838834764831845f;  // 1/sqrt(128) pre-applied to Q
    o2 *= 0.08838834764831845f;
  }
  qkv[base + i]      = f2b(o1);
  qkv[base + 64 + i] = f2b(o2);
}

// ---------------- V: qkv[token][5120+kv*128+d] -> Vt[b*8+kv][d][s] ----------------
__global__ void vtrans(const ushort* __restrict__ qkv, ushort* __restrict__ Vt) {
  __shared__ ushort tile[32][33];
  const int dt = blockIdx.x * 32, st = blockIdx.y * 32, bk = blockIdx.z;
  const int b = bk >> 3, kv = bk & 7;
  const int x = threadIdx.x, y = threadIdx.y;  // (32,8)
#pragma unroll
  for (int i = 0; i < 32; i += 8)
    tile[y + i][x] =
        qkv[(size_t)(b * S_LEN + st + y + i) * NQKV + 5120 + kv * HD + dt + x];
  __syncthreads();
#pragma unroll
  for (int i = 0; i < 32; i += 8)
    Vt[((size_t)bk * HD + dt + y + i) * S_LEN + st + x] = tile[x][y + i];
}

// ---------------- flash attention v3 ----------------
// Block = 256 threads = 4 waves = the 4 q-heads of one kv-head; each wave owns 32
// q rows. WORK PAIRING: block processes q-tiles {qp, 63-qp} sequentially => every
// block does exactly 65 k-tiles (tail eliminated; grid 512 = 2 blocks/CU flat).
// Swapped QK^T (mfma(K,Q)) keeps softmax lane-local. Steady-state softmax has ZERO
// cross-lane ops: defer-max checks lane-local max vs mi+8 (__any ballot), li kept
// as per-lane partials reduced once per segment. K then V loads hoisted to tile
// top so V latency hides under softmax (QK waits vmcnt(8), PV waits vmcnt(0)).
__global__ __launch_bounds__(256) void attn_fa(ushort* __restrict__ qkv,
                                               const ushort* __restrict__ Vt) {
  // XCD-contiguous swizzle: 512 blocks, 64 consecutive per XCD => each XCD's L2
  // touches ~2 (b,kvh) K/V working sets (~2 MB).
  const int lin = blockIdx.x + 32 * blockIdx.y + 256 * blockIdx.z;
  const int swz = (lin & 7) * 64 + (lin >> 3);
  const int qp = swz & 31;
  const int g  = swz >> 5;
  const int kvh = g & 7;
  const int b   = g >> 3;

  const int wid  = threadIdx.x >> 6;
  const int lane = threadIdx.x & 63;
  const int lr = lane & 15, lg = lane >> 4;
  const int h  = kvh * 4 + wid;

  const ushort* K = qkv + (size_t)(b * S_LEN) * NQKV + HID + kvh * HD;
  const ushort* V = Vt + (size_t)(b * NKV + kvh) * (HD * S_LEN);

  __shared__ ushort P[4][2][16 * 40];  // [wave][qtile][row][k padded 32->40]

  for (int seg = 0; seg < 2; ++seg) {
    const int qt = seg ? (63 - qp) : qp;
    const int q0 = qt * 32;
    const ushort* Q = qkv + (size_t)(b * S_LEN + q0) * NQKV + h * HD;

    // Q fragments: qf[t][kb] = Q[t*16+lr][kb*32 + lg*8 .. +7]
    bf16x8 qf[2][4];
#pragma unroll
    for (int t = 0; t < 2; ++t)
#pragma unroll
      for (int kb = 0; kb < 4; ++kb)
        qf[t][kb] = *(const bf16x8*)(Q + (size_t)(t * 16 + lr) * NQKV + kb * 32 + lg * 8);

    f32x4 o[2][8];
#pragma unroll
    for (int t = 0; t < 2; ++t)
#pragma unroll
      for (int c = 0; c < 8; ++c) o[t][c] = (f32x4){0.f, 0.f, 0.f, 0.f};
    float mi[2]  = {-1e30f, -1e30f};
    float lip[2] = {0.f, 0.f};  // per-lane partial row-sums; reduced once at end

    for (int k0 = 0; k0 <= q0; k0 += 32) {
      // ---- hoisted loads: K first (QK waits vmcnt(8)), V second (in flight
      // through softmax; PV waits vmcnt(0)) ----
      bf16x8 kf[2][4];
#pragma unroll
      for (int kb = 0; kb < 4; ++kb) {
        kf[0][kb] = *(const bf16x8*)(K + (size_t)(k0 + lr) * NQKV + kb * 32 + lg * 8);
        kf[1][kb] = *(const bf16x8*)(K + (size_t)(k0 + 16 + lr) * NQKV + kb * 32 + lg * 8);
      }
      bf16x8 vf[8];
#pragma unroll
      for (int c = 0; c < 8; ++c)
        vf[c] = *(const bf16x8*)(V + (size_t)(c * 16 + lr) * S_LEN + k0 + lg * 8);

      // S^T[k][q] = mfma(K,Q): col(lr)=q within tile t, row(lg*4+r)=k within u.
      f32x4 s[2][2];
#pragma unroll
      for (int t = 0; t < 2; ++t)
#pragma unroll
        for (int u = 0; u < 2; ++u) s[t][u] = (f32x4){0.f, 0.f, 0.f, 0.f};

      __builtin_amdgcn_s_setprio(1);
#pragma unroll
      for (int kb = 0; kb < 4; ++kb) {
        s[0][0] = __builtin_amdgcn_mfma_f32_16x16x32_bf16(kf[0][kb], qf[0][kb], s[0][0], 0, 0, 0);
        s[1][0] = __builtin_amdgcn_mfma_f32_16x16x32_bf16(kf[0][kb], qf[1][kb], s[1][0], 0, 0, 0);
        s[0][1] = __builtin_amdgcn_mfma_f32_16x16x32_bf16(kf[1][kb], qf[0][kb], s[0][1], 0, 0, 0);
        s[1][1] = __builtin_amdgcn_mfma_f32_16x16x32_bf16(kf[1][kb], qf[1][kb], s[1][1], 0, 0, 0);
      }
      __builtin_amdgcn_s_setprio(0);

      if (k0 == q0) {  // causal mask, only the diagonal tile needs it
#pragma unroll
        for (int t = 0; t < 2; ++t)
#pragma unroll
          for (int u = 0; u < 2; ++u)
#pragma unroll
            for (int r = 0; r < 4; ++r)
              if (u * 16 + lg * 4 + r > t * 16 + lr) s[t][u][r] = -1e30f;
      }

      // lane-local tile max (no cross-lane ops in steady state)
      float pm[2];
#pragma unroll
      for (int t = 0; t < 2; ++t) {
        float a = fmaxf(fmaxf(s[t][0][0], s[t][0][1]), fmaxf(s[t][0][2], s[t][0][3]));
        float c = fmaxf(fmaxf(s[t][1][0], s[t][1][1]), fmaxf(s[t][1][2], s[t][1][3]));
        pm[t] = fmaxf(a, c);
      }

      // defer-max: full reduce + rescale only when lane-local max grew past mi+8
      if (__any((pm[0] > mi[0] + 8.f) || (pm[1] > mi[1] + 8.f))) {
#pragma unroll
        for (int t = 0; t < 2; ++t) {
          float m = pm[t];
          m = fmaxf(m, __shfl_xor(m, 16));
          m = fmaxf(m, __shfl_xor(m, 32));
          const float mn = fmaxf(mi[t], m);
          const float al = __expf(mi[t] - mn);
          mi[t] = mn;
          lip[t] *= al;
#pragma unroll
          for (int r = 0; r < 4; ++r) {
            const float ar = __shfl(al, lg * 4 + r);  // o rows are q=lg*4+r
#pragma unroll
            for (int c = 0; c < 8; ++c) o[t][c][r] *= ar;
          }
        }
      }

#pragma unroll
      for (int t = 0; t < 2; ++t) {
        float p[2][4];
#pragma unroll
        for (int u = 0; u < 2; ++u)
#pragma unroll
          for (int r = 0; r < 4; ++r) p[u][r] = __expf(s[t][u][r] - mi[t]);
        lip[t] += ((p[0][0] + p[0][1]) + (p[0][2] + p[0][3])) +
                  ((p[1][0] + p[1][1]) + (p[1][2] + p[1][3]));
        ushort* Pw = &P[wid][t][0];
#pragma unroll
        for (int u = 0; u < 2; ++u) {
          const uint w0 = cvt_pk_bf16(p[u][0], p[u][1]);
          const uint w1 = cvt_pk_bf16(p[u][2], p[u][3]);
          *(uint2*)(Pw + lr * 40 + u * 16 + lg * 4) = make_uint2(w0, w1);
        }
      }
      // A-fragment of P: row=lr, k=lg*8..+7 (in-wave LDS transpose, no barrier)
      const bf16x8 pa0 = *(const bf16x8*)(&P[wid][0][0] + lr * 40 + lg * 8);
      const bf16x8 pa1 = *(const bf16x8*)(&P[wid][1][0] + lr * 40 + lg * 8);

      __builtin_amdgcn_s_setprio(1);
#pragma unroll
      for (int c = 0; c < 8; ++c) {
        o[0][c] = __builtin_amdgcn_mfma_f32_16x16x32_bf16(pa0, vf[c], o[0][c], 0, 0, 0);
        o[1][c] = __builtin_amdgcn_mfma_f32_16x16x32_bf16(pa1, vf[c], o[1][c], 0, 0, 0);
      }
      __builtin_amdgcn_s_setprio(0);
    }

    // one cross-lane li reduction per segment
    float linv[2];
#pragma unroll
    for (int t = 0; t < 2; ++t) {
      float rt = lip[t];
      rt += __shfl_xor(rt, 16);
      rt += __shfl_xor(rt, 32);
      linv[t] = 1.f / rt;
    }
#pragma unroll
    for (int t = 0; t < 2; ++t) {
#pragma unroll
      for (int r = 0; r < 4; ++r) {
        const float ir = __shfl(linv[t], lg * 4 + r);
        const size_t row = (size_t)(b * S_LEN + q0 + t * 16 + lg * 4 + r) * NQKV + h * HD;
#pragma unroll
        for (int c = 0; c < 8; ++c) qkv[row + c * 16 + lr] = f2b(o[t][c][r] * ir);
      }
    }
  }
}

extern "C" void kernel_launch(void* const* d_in, const int* in_sizes, int n_in,
                              void* d_out, int out_size, void* d_ws, size_t ws_size,
                              hipStream_t stream) {
  const float* hidden = (const float*)d_in[1];
  const float* w_qkv  = (const float*)d_in[2];
  const float* w_o    = (const float*)d_in[3];
  float* out = (float*)d_out;
  char* ws = (char*)d_ws;

  // workspace layout (128 MiB):
  // R0 [0, 48 MiB)   : wqkvT bf16 [6144][4096]; after gemm1: Vt bf16 [16][128][2048]
  // R1 [48, 80 MiB)  : hb bf16 [4096][4096];    after gemm1: woT bf16 [4096][4096]
  // R2 [80, 128 MiB) : qkv bf16 [4096][6144]; rope in-place; attn into q slots
  ushort* wqkvT = (ushort*)(ws);
  ushort* Vt    = (ushort*)(ws);
  ushort* hb    = (ushort*)(ws + (48u << 20));
  ushort* woT   = (ushort*)(ws + (48u << 20));
  ushort* qkvb  = (ushort*)(ws + (80u << 20));

  // 1) weight + activation prep
  trans_f32_bf16<<<dim3(192, 128), dim3(32, 8), 0, stream>>>(w_qkv, wqkvT, HID, NQKV);
  cvt_bf16<<<16384, 256, 0, stream>>>(hidden, hb, NB * S_LEN * HID);
  // 2) qkv = hb @ wqkvT^T
  gemm_nt<ushort><<<dim3(48, 32), 256, 0, stream>>>(
      hb, wqkvT, qkvb, NB * S_LEN, NQKV, HID, HID, HID);
  // 3) RoPE in-place (q pre-scaled by 1/sqrt(D))
  rope_qk<<<40960, 256, 0, stream>>>(qkvb);
  // 4) V -> Vt[d][s]  (into dead wqkvT region)
  vtrans<<<dim3(4, 64, 16), dim3(32, 8), 0, stream>>>(qkvb, Vt);
  // 5) w_o -> woT (into dead hb region)
  trans_f32_bf16<<<dim3(128, 128), dim3(32, 8), 0, stream>>>(w_o, woT, HID, HID);
  // 6) flash attention v3: paired q-tiles {qp, 63-qp}, 512 equal-work blocks
  attn_fa<<<dim3(32, 8, 2), 256, 0, stream>>>(qkvb, Vt);
  // 7) out = attn @ woT^T
  gemm_nt<float><<<dim3(32, 32), 256, 0, stream>>>(
      qkvb, woT, out, NB * S_LEN, HID, HID, NQKV, HID);
}